// Round 9
// baseline (199.530 us; speedup 1.0000x reference)
//
#include <hip/hip_runtime.h>
#include <math.h>

#define BH 64
#define NN 8192
#define DD 64
#define MM 32

#define NROWS (BH*NN)            // 524288
#define NORMC 0.35355339059327379f   // 64^-0.25
#define RATIO 0.17677669529663689f   // 32^-0.5
#define EPSK  1e-4f
#define DIAGC 0.0625f                // 0.5 * 64^-0.5

#define CPB 16                   // chunks per batch in kv kernel
#define CHUNK 512                // rows per chunk
#define K2_BLOCKS (BH*CPB)       // 1024

typedef __attribute__((ext_vector_type(8))) short short8;
typedef __attribute__((ext_vector_type(4))) float f32x4;

union FragU { uint4 u; short8 s; };

// round-to-nearest-even fp32 -> bf16 (bits in low 16)
__device__ __forceinline__ unsigned bf16r(float x) {
  unsigned u = __float_as_uint(x);
  return (u + 0x7fffu + ((u >> 16) & 1u)) >> 16;
}
// 8 fp32 -> hi/lo bf16x8 fragments (split: x = hi + lo)
__device__ __forceinline__ void cvt8(const float* f, FragU& hi, FragU& lo) {
  unsigned h[8], lw[8];
  #pragma unroll
  for (int j = 0; j < 8; ++j) {
    h[j] = bf16r(f[j]);
    lw[j] = bf16r(f[j] - __uint_as_float(h[j] << 16));
  }
  hi.u = make_uint4(h[0]|(h[1]<<16),  h[2]|(h[3]<<16),  h[4]|(h[5]<<16),  h[6]|(h[7]<<16));
  lo.u = make_uint4(lw[0]|(lw[1]<<16), lw[2]|(lw[3]<<16), lw[4]|(lw[5]<<16), lw[6]|(lw[7]<<16));
}

#define MFMA(a,b,c) __builtin_amdgcn_mfma_f32_16x16x32_bf16((a),(b),(c),0,0,0)

__device__ __forceinline__ float wave_max(float v) {
  #pragma unroll
  for (int off = 32; off > 0; off >>= 1)
    v = fmaxf(v, __shfl_down(v, off, 64));
  return v;
}

// ---------------- proj fragments: hi/lo bf16x8 per (mt,ks,lane) -------------
// B-frag (16x16x32): lane l holds B[k=(l>>4)*8+j][n=l&15]; B = proj^T so
// value = proj[mt*16 + (l&15)][ks*32 + (l>>4)*8 + j].
__global__ void kfrag_proj(const float* __restrict__ proj,
                           uint4* __restrict__ pfH, uint4* __restrict__ pfL)
{
  const int t = threadIdx.x;
  const int l = t & 63, g = t >> 6;          // g = mt*2 + ks
  const int mt = g >> 1, ks = g & 1;
  const int lr = l & 15, lg = l >> 4;
  float f[8];
  #pragma unroll
  for (int j = 0; j < 8; ++j)
    f[j] = proj[(mt*16 + lr)*DD + ks*32 + lg*8 + j];
  FragU hi, lo; cvt8(f, hi, lo);
  pfH[g*64 + l] = hi.u;
  pfL[g*64 + l] = lo.u;
}

// ---------------- K1: dash via MFMA, LDS-FREE; E' -> sBuf row-major ---------
// dash stays in the MFMA C-layout (lane l holds rows lg*4+reg, cols lr and
// lr+16). diag reaches the right lanes via 2 shfl_xor (ssq over lg) + 1
// bpermute per reg (row r's ssq lives at src lane lr==r, same wave/rt).
// exp is elementwise in-layout; E' stored row-major with dword stores (lanes
// lr consecutive -> 4 full 64B segments per inst). Only 16B of LDS -> 
// occupancy is VGPR-bound; rt iterations independent -> loads pipeline.
__global__ __launch_bounds__(256, 5) void k1_dash_max(
    const float* __restrict__ k,
    const uint4* __restrict__ pfH, const uint4* __restrict__ pfL,
    float* __restrict__ partialMax, float* __restrict__ sOut)
{
  __shared__ float wmax[4];
  const int t = threadIdx.x;
  const int w = t >> 6, l = t & 63;
  const int lr = l & 15, lg = l >> 4;
  const size_t rowBase = (size_t)blockIdx.x * 256;
  const int wrb = w * 64;

  FragU pbH[2][2], pbL[2][2];
  #pragma unroll
  for (int mt = 0; mt < 2; ++mt)
    #pragma unroll
    for (int ks = 0; ks < 2; ++ks) {
      pbH[mt][ks].u = pfH[(mt*2+ks)*64 + l];
      pbL[mt][ks].u = pfL[(mt*2+ks)*64 + l];
    }

  float tmax = -3.4e38f;
  #pragma unroll
  for (int rt = 0; rt < 4; ++rt) {
    const int rrow = wrb + rt*16 + lr;       // row this lane LOADS
    f32x4 acc0 = {0.f,0.f,0.f,0.f}, acc1 = {0.f,0.f,0.f,0.f};
    float sq = 0.f;
    FragU aH[2], aL[2];
    #pragma unroll
    for (int ks = 0; ks < 2; ++ks) {
      const float4* src = (const float4*)(k + (rowBase + rrow)*DD + ks*32 + lg*8);
      float4 a0 = src[0], a1 = src[1];
      float qv[8] = {a0.x,a0.y,a0.z,a0.w, a1.x,a1.y,a1.z,a1.w};
      #pragma unroll
      for (int j = 0; j < 8; ++j) sq += qv[j]*qv[j];
      cvt8(qv, aH[ks], aL[ks]);
    }
    // full-row ssq: sum the 4 lg-slices (lanes l, l^16, l^32, l^48)
    sq += __shfl_xor(sq, 16, 64);
    sq += __shfl_xor(sq, 32, 64);
    #pragma unroll
    for (int ks = 0; ks < 2; ++ks) {
      acc0 = MFMA(aL[ks].s, pbH[0][ks].s, acc0);
      acc0 = MFMA(aH[ks].s, pbL[0][ks].s, acc0);
      acc0 = MFMA(aH[ks].s, pbH[0][ks].s, acc0);
      acc1 = MFMA(aL[ks].s, pbH[1][ks].s, acc1);
      acc1 = MFMA(aH[ks].s, pbL[1][ks].s, acc1);
      acc1 = MFMA(aH[ks].s, pbH[1][ks].s, acc1);
    }
    // per-reg: this lane owns row (lg*4+reg), cols lr (acc0) and lr+16 (acc1)
    float* so = sOut + (rowBase + wrb + rt*16) * MM;
    #pragma unroll
    for (int reg = 0; reg < 4; ++reg) {
      const float diag = DIAGC * __shfl(sq, lg*4 + reg, 64);  // bpermute
      const float a0v = acc0[reg] * NORMC;
      const float a1v = acc1[reg] * NORMC;
      tmax = fmaxf(tmax, fmaxf(a0v, a1v));
      const float e0 = __expf(a0v - diag);
      const float e1 = __expf(a1v - diag);
      if (sOut) {
        so[(lg*4 + reg)*MM + lr]      = e0;
        so[(lg*4 + reg)*MM + 16 + lr] = e1;
      }
    }
  }
  tmax = wave_max(tmax);
  if (l == 0) wmax[w] = tmax;
  __syncthreads();
  if (t == 0)
    partialMax[blockIdx.x] = fmaxf(fmaxf(wmax[0], wmax[1]), fmaxf(wmax[2], wmax[3]));
}

// ---------------- K1b: reduce partial maxes -> global max -------------------
__global__ __launch_bounds__(256) void k1b_reduce_max(
    const float* __restrict__ partialMax, float* __restrict__ gmax)
{
  const int t = threadIdx.x;
  float mx = -3.4e38f;
  for (int i = t; i < 2048; i += 256) mx = fmaxf(mx, partialMax[i]);
  mx = wave_max(mx);
  __shared__ float wmaxs[4];
  if ((t & 63) == 0) wmaxs[t >> 6] = mx;
  __syncthreads();
  if (t == 0)
    *gmax = fmaxf(fmaxf(wmaxs[0], wmaxs[1]), fmaxf(wmaxs[2], wmaxs[3]));
}

// ---------------- K2: E' outer-product partials (+vsum) — unchanged ---------
template<bool USE_S>
__global__ __launch_bounds__(256) void k2_kv(
    const float* __restrict__ k, const float* __restrict__ v,
    const float* __restrict__ proj, const float* __restrict__ sBuf,
    float* __restrict__ kvPart, float* __restrict__ ksPart,
    float* __restrict__ vsPart)
{
  __shared__ float kpL[8][258][4];
  const int t = threadIdx.x;
  const int b = blockIdx.x >> 4;
  const int c = blockIdx.x & (CPB - 1);
  const size_t base = (size_t)b * NN + (size_t)c * CHUNK;

  const int dg = t & 7, mg = (t >> 3) & 7, ng = t >> 6;
  float acc[4][8];
  #pragma unroll
  for (int j = 0; j < 4; ++j)
    #pragma unroll
    for (int e = 0; e < 8; ++e) acc[j][e] = 0.f;
  float ksacc[4] = {0.f, 0.f, 0.f, 0.f};
  float vs[8] = {0.f,0.f,0.f,0.f,0.f,0.f,0.f,0.f};

  for (int st = 0; st < CHUNK / 256; ++st) {
    const size_t rbase = base + st * 256;
    {
      const size_t row = rbase + t;
      float p[MM];
      if (USE_S) {
        const float4* sr = (const float4*)(sBuf + row * MM);
        #pragma unroll
        for (int j = 0; j < 8; ++j) {
          float4 s4 = sr[j];
          p[4*j] = s4.x; p[4*j+1] = s4.y; p[4*j+2] = s4.z; p[4*j+3] = s4.w;
        }
      } else {
        const float4* kr = (const float4*)(k + row * DD);
        float4 kq[16];
        #pragma unroll
        for (int i = 0; i < 16; ++i) kq[i] = kr[i];
        float ssq = 0.f;
        #pragma unroll
        for (int i = 0; i < 16; ++i)
          ssq += kq[i].x*kq[i].x + kq[i].y*kq[i].y + kq[i].z*kq[i].z + kq[i].w*kq[i].w;
        const float diag = DIAGC * ssq;
        #pragma unroll
        for (int m = 0; m < MM; ++m) {
          const float4* pm = (const float4*)(proj + m * DD);
          float a = 0.f;
          #pragma unroll
          for (int i = 0; i < 16; ++i) {
            float4 p4 = pm[i];
            a = fmaf(kq[i].x, p4.x, a);
            a = fmaf(kq[i].y, p4.y, a);
            a = fmaf(kq[i].z, p4.z, a);
            a = fmaf(kq[i].w, p4.w, a);
          }
          p[m] = __expf(fmaf(a, NORMC, -diag));
        }
      }
      #pragma unroll
      for (int mb = 0; mb < 8; ++mb) {
        kpL[mb][t][0] = p[4*mb];
        kpL[mb][t][1] = p[4*mb+1];
        kpL[mb][t][2] = p[4*mb+2];
        kpL[mb][t][3] = p[4*mb+3];
      }
    }
    __syncthreads();
    {
      #pragma unroll 4
      for (int i = 0; i < 64; ++i) {
        const int n = (ng << 6) + i;
        const float4 kp4 = *(const float4*)&kpL[mg][n][0];
        const float4* vr = (const float4*)(v + (rbase + n) * DD + dg * 8);
        const float4 va = vr[0], vb = vr[1];
        #pragma unroll
        for (int j = 0; j < 4; ++j) {
          const float pj = (&kp4.x)[j];
          acc[j][0] = fmaf(pj, va.x, acc[j][0]);
          acc[j][1] = fmaf(pj, va.y, acc[j][1]);
          acc[j][2] = fmaf(pj, va.z, acc[j][2]);
          acc[j][3] = fmaf(pj, va.w, acc[j][3]);
          acc[j][4] = fmaf(pj, vb.x, acc[j][4]);
          acc[j][5] = fmaf(pj, vb.y, acc[j][5]);
          acc[j][6] = fmaf(pj, vb.z, acc[j][6]);
          acc[j][7] = fmaf(pj, vb.w, acc[j][7]);
          ksacc[j] += pj;
        }
        vs[0] += va.x; vs[1] += va.y; vs[2] += va.z; vs[3] += va.w;
        vs[4] += vb.x; vs[5] += vb.y; vs[6] += vb.z; vs[7] += vb.w;
      }
    }
    __syncthreads();
  }

  float* red = &kpL[0][0][0];
  #pragma unroll
  for (int j = 0; j < 4; ++j)
    #pragma unroll
    for (int e = 0; e < 8; ++e)
      red[t * 32 + j * 8 + e] = acc[j][e];
  __syncthreads();
  #pragma unroll
  for (int ii = 0; ii < 8; ++ii) {
    const int o = t + 256 * ii;
    const int m = o >> 6, d = o & 63;
    const int mg2 = m >> 2, j2 = m & 3, dg2 = d >> 3, e2 = d & 7;
    float s = 0.f;
    #pragma unroll
    for (int g = 0; g < 4; ++g)
      s += red[(dg2 + 8 * mg2 + 64 * g) * 32 + j2 * 8 + e2];
    kvPart[(size_t)blockIdx.x * 2048 + o] = s;
  }
  __syncthreads();
  if (dg == 0) {
    #pragma unroll
    for (int j = 0; j < 4; ++j)
      red[ng * 32 + mg * 4 + j] = ksacc[j];
  }
  __syncthreads();
  if (t < 32) {
    float s = red[t] + red[32 + t] + red[64 + t] + red[96 + t];
    ksPart[blockIdx.x * 32 + t] = s;
  }
  __syncthreads();
  if (mg == 0) {
    #pragma unroll
    for (int j = 0; j < 8; ++j)
      red[ng * 64 + dg * 8 + j] = vs[j];
  }
  __syncthreads();
  if (t < 64)
    vsPart[blockIdx.x * 64 + t] = red[t] + red[64 + t] + red[128 + t] + red[192 + t];
}

// ---------------- K2b: reduce -> kv values (LDS) -> ksF + kv B-fragments ----
__global__ __launch_bounds__(256) void k2b_reduce(
    const float* __restrict__ kvPart, const float* __restrict__ ksPart,
    const float* __restrict__ vsPart, const float* __restrict__ gmaxPtr,
    float* __restrict__ ksF, uint4* __restrict__ kfH, uint4* __restrict__ kfL)
{
  __shared__ float vsumL[64];
  __shared__ float kvL[2048];
  const int b = blockIdx.x, t = threadIdx.x;
  const float scale = __expf(-*gmaxPtr);
  if (t < 64) {
    float s = 0.f;
    for (int c = 0; c < CPB; ++c)
      s += vsPart[(b * CPB + c) * 64 + t];
    vsumL[t] = s;
  }
  __syncthreads();
  #pragma unroll
  for (int ii = 0; ii < 8; ++ii) {
    const int o = t + 256 * ii;
    float s = 0.f;
    for (int c = 0; c < CPB; ++c)
      s += kvPart[((size_t)(b * CPB + c)) * 2048 + o];
    kvL[o] = RATIO * (scale * s + EPSK * vsumL[o & 63]);
  }
  if (t < 32) {
    float s = 0.f;
    for (int c = 0; c < CPB; ++c)
      s += ksPart[(b * CPB + c) * 32 + t];
    ksF[b * 32 + t] = RATIO * (scale * s + EPSK * (float)NN);
  }
  __syncthreads();
  // B-frag (16x16x32): lane l holds kv[k=(l>>4)*8+j][d = dt*16 + (l&15)]
  {
    const int l = t & 63, dt = t >> 6;
    const int lr = l & 15, lg = l >> 4;
    float f[8];
    #pragma unroll
    for (int j = 0; j < 8; ++j)
      f[j] = kvL[(lg*8 + j)*64 + dt*16 + lr];
    FragU hi, lo; cvt8(f, hi, lo);
    kfH[(b*4 + dt)*64 + l] = hi.u;
    kfL[(b*4 + dt)*64 + l] = lo.u;
  }
}

// ---------------- K3: dash MFMA -> softmax -> num MFMA (barrier-free) -------
__global__ __launch_bounds__(256, 4) void k3_out(
    const float* __restrict__ q,
    const uint4* __restrict__ pfH, const uint4* __restrict__ pfL,
    const uint4* __restrict__ kfH, const uint4* __restrict__ kfL,
    const float* __restrict__ ksF, float* __restrict__ out)
{
  __shared__ float dashL[256][36];   // fp32 dash; reused per-row as packed pstar
  __shared__ float ssqL[256][4];
  const int t = threadIdx.x;
  const int w = t >> 6, l = t & 63;
  const int lr = l & 15, lg = l >> 4;
  const int b = blockIdx.x >> 5;
  const size_t rowBase = (size_t)blockIdx.x * 256;
  const int wrb = w * 64;

  FragU pbH[2][2], pbL[2][2];
  #pragma unroll
  for (int mt = 0; mt < 2; ++mt)
    #pragma unroll
    for (int ks = 0; ks < 2; ++ks) {
      pbH[mt][ks].u = pfH[(mt*2+ks)*64 + l];
      pbL[mt][ks].u = pfL[(mt*2+ks)*64 + l];
    }

  // phase A
  #pragma unroll
  for (int rt = 0; rt < 4; ++rt) {
    const int rrow = wrb + rt*16 + lr;
    f32x4 acc0 = {0.f,0.f,0.f,0.f}, acc1 = {0.f,0.f,0.f,0.f};
    float sq = 0.f;
    #pragma unroll
    for (int ks = 0; ks < 2; ++ks) {
      const float4* src = (const float4*)(q + (rowBase + rrow)*DD + ks*32 + lg*8);
      float4 a0 = src[0], a1 = src[1];
      float qv[8] = {a0.x,a0.y,a0.z,a0.w, a1.x,a1.y,a1.z,a1.w};
      #pragma unroll
      for (int j = 0; j < 8; ++j) sq += qv[j]*qv[j];
      FragU aH, aL; cvt8(qv, aH, aL);
      acc0 = MFMA(aL.s, pbH[0][ks].s, acc0);
      acc0 = MFMA(aH.s, pbL[0][ks].s, acc0);
      acc0 = MFMA(aH.s, pbH[0][ks].s, acc0);
      acc1 = MFMA(aL.s, pbH[1][ks].s, acc1);
      acc1 = MFMA(aH.s, pbL[1][ks].s, acc1);
      acc1 = MFMA(aH.s, pbH[1][ks].s, acc1);
    }
    ssqL[rrow][lg] = sq;
    #pragma unroll
    for (int reg = 0; reg < 4; ++reg) {
      dashL[wrb + rt*16 + lg*4 + reg][lr]      = acc0[reg];
      dashL[wrb + rt*16 + lg*4 + reg][16 + lr] = acc1[reg];
    }
  }

  // softmax phase: thread t owns row t (same wave as its stripe: no barrier)
  {
    float dv[32];
    const float4* dr = (const float4*)&dashL[t][0];
    #pragma unroll
    for (int i = 0; i < 8; ++i) {
      float4 v4 = dr[i];
      dv[4*i]=v4.x; dv[4*i+1]=v4.y; dv[4*i+2]=v4.z; dv[4*i+3]=v4.w;
    }
    const float ssq = ssqL[t][0]+ssqL[t][1]+ssqL[t][2]+ssqL[t][3];
    float mx = -3.4e38f;
    #pragma unroll
    for (int m = 0; m < MM; ++m) { dv[m] *= NORMC; mx = fmaxf(mx, dv[m]); }
    const float sub = DIAGC * ssq + mx;
    const float* __restrict__ ksb = ksF + b * 32;
    float den = 0.f;
    #pragma unroll
    for (int m = 0; m < MM; ++m) {
      dv[m] = RATIO * (__expf(dv[m] - sub) + EPSK);
      den = fmaf(dv[m], ksb[m], den);
    }
    const float inv = 1.0f / den;
    unsigned hiw[16], low[16];
    #pragma unroll
    for (int u = 0; u < 16; ++u) {
      const float x0 = dv[2*u] * inv, x1 = dv[2*u+1] * inv;
      const unsigned h0 = bf16r(x0);
      const unsigned l0 = bf16r(x0 - __uint_as_float(h0 << 16));
      const unsigned h1 = bf16r(x1);
      const unsigned l1 = bf16r(x1 - __uint_as_float(h1 << 16));
      hiw[u] = h0 | (h1 << 16);
      low[u] = l0 | (l1 << 16);
    }
    uint4* pr = (uint4*)&dashL[t][0];   // overwrite own row only
    pr[0] = make_uint4(hiw[0],hiw[1],hiw[2],hiw[3]);
    pr[1] = make_uint4(hiw[4],hiw[5],hiw[6],hiw[7]);
    pr[2] = make_uint4(hiw[8],hiw[9],hiw[10],hiw[11]);
    pr[3] = make_uint4(hiw[12],hiw[13],hiw[14],hiw[15]);
    pr[4] = make_uint4(low[0],low[1],low[2],low[3]);
    pr[5] = make_uint4(low[4],low[5],low[6],low[7]);
    pr[6] = make_uint4(low[8],low[9],low[10],low[11]);
    pr[7] = make_uint4(low[12],low[13],low[14],low[15]);
  }

  // phase B: out = pstar · kv (K=32, one k-step, 3 comp terms)
  FragU kbH[4], kbL[4];
  #pragma unroll
  for (int dt = 0; dt < 4; ++dt) {
    kbH[dt].u = kfH[(b*4 + dt)*64 + l];
    kbL[dt].u = kfL[(b*4 + dt)*64 + l];
  }
  #pragma unroll
  for (int rt = 0; rt < 4; ++rt) {
    const uint4* pr = (const uint4*)&dashL[wrb + rt*16 + lr][0];
    FragU aH, aL;
    aH.u = pr[lg];
    aL.u = pr[4 + lg];
    #pragma unroll
    for (int dt = 0; dt < 4; ++dt) {
      f32x4 o = {0.f,0.f,0.f,0.f};
      o = MFMA(aL.s, kbH[dt].s, o);
      o = MFMA(aH.s, kbL[dt].s, o);
      o = MFMA(aH.s, kbH[dt].s, o);
      float* ob = out + (rowBase + wrb + rt*16 + lg*4)*DD + dt*16 + lr;
      ob[0]      = o[0];
      ob[DD]     = o[1];
      ob[2*DD]   = o[2];
      ob[3*DD]   = o[3];
    }
  }
}

// ---------------- host ------------------------------------------------------
extern "C" void kernel_launch(void* const* d_in, const int* in_sizes, int n_in,
                              void* d_out, int out_size, void* d_ws, size_t ws_size,
                              hipStream_t stream) {
  const float* q    = (const float*)d_in[0];
  const float* k    = (const float*)d_in[1];
  const float* v    = (const float*)d_in[2];
  const float* proj = (const float*)d_in[3];
  float* out = (float*)d_out;
  float* ws  = (float*)d_ws;

  float*    partialMax = ws;                       // 2048
  float*    gmax       = ws + 2048;                // (pad to 4096)
  float*    kvPart     = ws + 4096;                // 1024*2048
  float*    ksPart     = kvPart + 2097152;         // 1024*32
  float*    vsPart     = ksPart + 32768;           // 1024*64
  float*    ksF        = vsPart + 65536;           // 64*32 (pad 2048)
  unsigned* pfH        = (unsigned*)(ksF + 2048);  // 4*64 uint4 = 1024 words
  unsigned* pfL        = pfH + 1024;               // 1024
  unsigned* kfH        = pfL + 1024;               // 64*4*64 uint4 = 65536 words
  unsigned* kfL        = kfH + 65536;              // 65536
  float*    sBuf       = (float*)(kfL + 65536);    // 524288*32 floats (64 MB)
  const size_t baseFloats = 4096 + 2097152 + 32768 + 65536 + 2048
                          + 1024 + 1024 + 65536 + 65536;   // 2334720
  const bool useS = ws_size >= (baseFloats + (size_t)NROWS * MM) * sizeof(float);

  kfrag_proj<<<1, 256, 0, stream>>>(proj, (uint4*)pfH, (uint4*)pfL);
  k1_dash_max<<<NROWS / 256, 256, 0, stream>>>(k, (uint4*)pfH, (uint4*)pfL,
                                               partialMax, useS ? sBuf : nullptr);
  k1b_reduce_max<<<1, 256, 0, stream>>>(partialMax, gmax);
  if (useS)
    k2_kv<true><<<K2_BLOCKS, 256, 0, stream>>>(k, v, proj, sBuf,
                                               kvPart, ksPart, vsPart);
  else
    k2_kv<false><<<K2_BLOCKS, 256, 0, stream>>>(k, v, proj, sBuf,
                                                kvPart, ksPart, vsPart);
  k2b_reduce<<<BH, 256, 0, stream>>>(kvPart, ksPart, vsPart, gmax,
                                     ksF, (uint4*)kfH, (uint4*)kfL);
  k3_out<<<NROWS / 256, 256, 0, stream>>>(q, (uint4*)pfH, (uint4*)pfL,
                                          (uint4*)kfH, (uint4*)kfL, ksF, out);
}